// Round 14
// baseline (136.254 us; speedup 1.0000x reference)
//
#include <hip/hip_runtime.h>

#define SEQ 2048
#define CDIM 1024
#define NHEAD 16
#define HDIM 64

typedef __bf16 bf16x8 __attribute__((ext_vector_type(8)));
typedef __bf16 bf16x4v __attribute__((ext_vector_type(4)));
typedef float f32x4 __attribute__((ext_vector_type(4)));

typedef const __attribute__((address_space(1))) char* gcp_t;
typedef __attribute__((address_space(3))) char* lcp_t;

__device__ __forceinline__ void gload16(const void* g, void* l) {
    __builtin_amdgcn_global_load_lds((gcp_t)g, (lcp_t)l, 16, 0, 0);
}

__device__ __forceinline__ unsigned short f2bf(float f) {
    unsigned int u = __float_as_uint(f);
    u += 0x7fffu + ((u >> 16) & 1u);
    return (unsigned short)(u >> 16);
}

// 64B-row LDS swizzle (proven zero bank conflicts r6/r7): row bit0 alternates
// 64B halves, bits 1-2 rotate 16B slots. Applied on pre-swizzled global source
// (gload dest linear) and identically on ds_read (rule #21 involution).
__device__ __forceinline__ int swz16(int r) { return ((r >> 1) & 3) << 4; }

// ---------------- fused precompute: bf16 converts + RoPE table ------------
__global__ void cvt_rope_all(const float* __restrict__ x,
                             const float* __restrict__ Wq, const float* __restrict__ Wk,
                             const float* __restrict__ Wv, const float* __restrict__ Wp,
                             unsigned short* __restrict__ xb,
                             unsigned short* __restrict__ wqkv, unsigned short* __restrict__ wpb,
                             float2* __restrict__ cstab) {
    int i = blockIdx.x * blockDim.x + threadIdx.x;
    if (i < 2097152) {
        const float* s;
        unsigned short* d;
        int r;
        if (i < 1048576) { s = x; d = xb; r = i; }
        else {
            int j = i - 1048576;
            int which = j >> 18; r = j & 262143;
            s = (which == 0) ? Wq : (which == 1) ? Wk : (which == 2) ? Wv : Wp;
            d = (which < 3) ? (wqkv + (size_t)which * 1048576) : wpb;
        }
        float4 v = ((const float4*)s)[r];
        ushort4 o;
        o.x = f2bf(v.x); o.y = f2bf(v.y); o.z = f2bf(v.z); o.w = f2bf(v.w);
        ((ushort4*)d)[r] = o;
    } else {
        int idx = i - 2097152;          // 0 .. 65535
        int j = idx & 31, t = idx >> 5;
        // faithful to ref: theta = 1/10000**(-2*(j-1)/64), f32 roundings kept
        float e = -2.0f * ((float)j - 1.0f) / 64.0f;
        float denom = (float)pow(10000.0, (double)e);
        float theta = 1.0f / denom;
        float ang = (float)t * theta;
        cstab[idx] = make_float2(cosf(ang), sinf(ang));
    }
}

// ---------------- GEMM (C = A * B^T), BK=32, 2-phase dbuf + swz16 ----------
// MODE 0 (BM=128): A=x[4096][1024], B=Wqkv[3072][1024]; bias+RoPE epilogue,
//   q (pre-scaled 0.125*log2e), k as [B,H,T,D] bf16, v^T as [B,H,D,T] bf16.
// MODE 1 (BM=64): A=y[4096][1024], B=Wp[1024][1024]; bias, f32 out.
template <int MODE, int BM>
__global__ __launch_bounds__(256) void gemm_bt(
    const unsigned short* __restrict__ A, const unsigned short* __restrict__ Bm,
    const float* __restrict__ b0, const float* __restrict__ b1, const float* __restrict__ b2,
    unsigned short* __restrict__ qb, unsigned short* __restrict__ kb,
    unsigned short* __restrict__ vtb, float* __restrict__ outf,
    const float2* __restrict__ cstab)
{
    constexpr int K = 1024;
    constexpr int NIT = K / 32;
    constexpr int NR = (BM == 128) ? 4 : 2;
    __shared__ __align__(16) char As[2][BM * 64];
    __shared__ __align__(16) char Bs[2][128 * 64];
    const int tid = threadIdx.x, lane = tid & 63, wid = tid >> 6;
    const int m0 = blockIdx.y * BM, n0 = blockIdx.x * 128;
    const int wr = (BM == 128) ? ((wid >> 1) * 64) : 0;
    const int wc = (BM == 128) ? ((wid & 1) * 64) : (wid * 32);

    f32x4 acc[4][NR] = {};

    const char* Ag = (const char*)(A + (size_t)m0 * K);
    const char* Bg = (const char*)(Bm + (size_t)n0 * K);
    const int r0 = tid >> 2, cb = (tid & 3) * 16;
    const int ldsw = wid << 10;

    auto stage = [&](int k0, int bufi) {
        char* Ad = As[bufi];
        char* Bd = Bs[bufi];
        gload16(Ag + (size_t)r0 * 2048 + k0 * 2 + (cb ^ swz16(r0)), Ad + ldsw);
        if constexpr (BM == 128)
            gload16(Ag + (size_t)(r0 + 64) * 2048 + k0 * 2 + (cb ^ swz16(r0 + 64)), Ad + 4096 + ldsw);
        gload16(Bg + (size_t)r0 * 2048 + k0 * 2 + (cb ^ swz16(r0)), Bd + ldsw);
        gload16(Bg + (size_t)(r0 + 64) * 2048 + k0 * 2 + (cb ^ swz16(r0 + 64)), Bd + 4096 + ldsw);
    };

    stage(0, 0);
    __syncthreads();

    for (int it = 0; it < NIT; ++it) {
        const int cur = it & 1;
        if (it + 1 < NIT) stage((it + 1) * 32, cur ^ 1);
        const char* Ac = As[cur];
        const char* Bc = Bs[cur];
        const int fs = (lane >> 4) * 16;
        bf16x8 af[4], bfr[NR];
#pragma unroll
        for (int am = 0; am < 4; ++am) {
            const int r = wr + am * 16 + (lane & 15);
            af[am] = *(const bf16x8*)(Ac + r * 64 + (fs ^ swz16(r)));
        }
#pragma unroll
        for (int an = 0; an < NR; ++an) {
            const int r = wc + an * 16 + (lane & 15);
            bfr[an] = *(const bf16x8*)(Bc + r * 64 + (fs ^ swz16(r)));
        }
#pragma unroll
        for (int am = 0; am < 4; ++am)
#pragma unroll
            for (int an = 0; an < NR; ++an)
                acc[am][an] = __builtin_amdgcn_mfma_f32_16x16x32_bf16(af[am], bfr[an], acc[am][an], 0, 0, 0);
        __syncthreads();
    }

    if (MODE == 0) {
        const float QSCL = 0.18033688011112042f;  // 0.125 * log2(e)
#pragma unroll
        for (int an = 0; an < NR; ++an) {
            const int ng = n0 + wc + an * 16 + (lane & 15);
            const int which = ng >> 10, nl = ng & 1023;
            const int h = nl >> 6, d = nl & 63;
            const float* bptr = (which == 0) ? b0 : (which == 1) ? b1 : b2;
            const float bias = bptr[nl];
            if (which < 2) {
                unsigned short* dst = (which == 0) ? qb : kb;
                const float qs = (which == 0) ? QSCL : 1.0f;
                const int j = d >> 1;
#pragma unroll
                for (int am = 0; am < 4; ++am) {
#pragma unroll
                    for (int i = 0; i < 4; ++i) {
                        const int row = m0 + wr + am * 16 + (lane >> 4) * 4 + i;
                        const int bb = row >> 11, t = row & 2047;
                        float v = acc[am][an][i] + bias;
                        float p = __shfl_xor(v, 1);
                        const float2 cs = cstab[t * 32 + j];
                        v = (d & 1) ? fmaf(v, cs.x, p * cs.y) : fmaf(v, cs.x, -p * cs.y);
                        dst[((size_t)((bb * 16 + h) * 2048 + t)) * 64 + d] = f2bf(v * qs);
                    }
                }
            } else {
#pragma unroll
                for (int am = 0; am < 4; ++am) {
                    const int rowb = m0 + wr + am * 16 + (lane >> 4) * 4;
                    const int bb = rowb >> 11, t = rowb & 2047;
                    ushort4 pk;
                    pk.x = f2bf(acc[am][an][0] + bias);
                    pk.y = f2bf(acc[am][an][1] + bias);
                    pk.z = f2bf(acc[am][an][2] + bias);
                    pk.w = f2bf(acc[am][an][3] + bias);
                    *(ushort4*)(vtb + ((size_t)((bb * 16 + h) * 64 + d)) * 2048 + t) = pk;
                }
            }
        }
    } else {
#pragma unroll
        for (int an = 0; an < NR; ++an) {
            const int col = n0 + wc + an * 16 + (lane & 15);
            const float bias = b0[col];
#pragma unroll
            for (int am = 0; am < 4; ++am)
#pragma unroll
                for (int i = 0; i < 4; ++i) {
                    const int row = m0 + wr + am * 16 + (lane >> 4) * 4 + i;
                    outf[(size_t)row * 1024 + col] = acc[am][an][i] + bias;
                }
        }
    }
}

// ---------------- flash attention: r4 inner loop, UNIFORM 2-qt blocks -----
// grid (16, 32) = 512 blocks, 2/CU. Each block processes qt = x then 31-x
// sequentially: exactly 33 KV-tiles per block -> zero intra-CU tail imbalance
// (the r4 version's 4-block pairing left CUs half-idle once short blocks
// finished; occupancy decayed to ~24%). Inner loop byte-identical to r4.
__global__ __launch_bounds__(256) void attn_kernel(
    const unsigned short* __restrict__ qb, const unsigned short* __restrict__ kb,
    const unsigned short* __restrict__ vtb, unsigned short* __restrict__ yb)
{
    __shared__ __align__(16) unsigned short Ks[2][64 * 64];
    __shared__ __align__(16) unsigned short Vs[2][64 * 64];
    __shared__ __align__(16) unsigned short Ps[4][16 * 64];
    const int tid = threadIdx.x, lane = tid & 63, wid = tid >> 6;
    const int bh = blockIdx.y;
    const int b = bh >> 4, h = bh & 15;
    const unsigned short* Qg = qb + (size_t)bh * SEQ * HDIM;
    const char* Kg = (const char*)(kb + (size_t)bh * SEQ * HDIM);
    const char* Vg = (const char*)(vtb + (size_t)bh * HDIM * SEQ);

    const int cr0 = tid >> 3, cc0 = ((tid & 7) * 16) ^ ((cr0 & 7) << 4);
    const int cr1 = cr0 + 32, cc1 = ((tid & 7) * 16) ^ ((cr1 & 7) << 4);
    const int ldsw = wid << 10;

    auto stage = [&](int kt, int bufi) {
        const size_t kv0 = (size_t)kt * 64;
        gload16(Kg + (kv0 + cr0) * 128 + cc0, (char*)Ks[bufi] + ldsw);
        gload16(Kg + (kv0 + cr1) * 128 + cc1, (char*)Ks[bufi] + 4096 + ldsw);
        gload16(Vg + (size_t)cr0 * 4096 + kv0 * 2 + cc0, (char*)Vs[bufi] + ldsw);
        gload16(Vg + (size_t)cr1 * 4096 + kv0 * 2 + cc1, (char*)Vs[bufi] + 4096 + ldsw);
    };

    for (int half = 0; half < 2; ++half) {
        const int qt = half ? (31 - blockIdx.x) : blockIdx.x;
        const int q0 = qt * 64;
        const int qw = q0 + wid * 16;

        bf16x8 qf[2];
#pragma unroll
        for (int kf = 0; kf < 2; ++kf)
            qf[kf] = *(const bf16x8*)(Qg + (size_t)(qw + (lane & 15)) * 64 + kf * 32 + (lane >> 4) * 8);

        f32x4 o[4] = {};                 // o[dn] : O^T[d][q]
        float mrun = -3e38f;
        float lrun = 0.0f;
        const int nt = qt + 1;

        stage(0, 0);
        __syncthreads();

        for (int kt = 0; kt < nt; ++kt) {
            const int cur = kt & 1;
            if (kt + 1 < nt) stage(kt + 1, cur ^ 1);
            const int kv0 = kt * 64;
            {
                f32x4 s[4] = {};
                __builtin_amdgcn_s_setprio(1);
#pragma unroll
                for (int kf = 0; kf < 2; ++kf) {
                    bf16x8 kfr[4];
#pragma unroll
                    for (int an = 0; an < 4; ++an) {
                        const int r = an * 16 + (lane & 15);
                        kfr[an] = *(const bf16x8*)((const char*)Ks[cur] + r * 128 + ((kf * 64 + (lane >> 4) * 16) ^ ((r & 7) << 4)));
                    }
#pragma unroll
                    for (int an = 0; an < 4; ++an)
                        s[an] = __builtin_amdgcn_mfma_f32_16x16x32_bf16(kfr[an], qf[kf], s[an], 0, 0, 0);
                }
                __builtin_amdgcn_s_setprio(0);
                const bool need_mask = (kv0 + 63 > qw);
                const int qg = qw + (lane & 15);
                const int kbase = kv0 + ((lane >> 4) << 2);
                float p[4][4];
                float mx = -3e38f;
#pragma unroll
                for (int an = 0; an < 4; ++an)
#pragma unroll
                    for (int i = 0; i < 4; ++i) {
                        float v = s[an][i];
                        if (need_mask && (kbase + an * 16 + i > qg)) v = -3e38f;
                        p[an][i] = v;
                        mx = fmaxf(mx, v);
                    }
                mx = fmaxf(mx, __shfl_xor(mx, 16));
                mx = fmaxf(mx, __shfl_xor(mx, 32));
                if (!__all(mx <= mrun + 8.0f)) {
                    const float mnew = fmaxf(mrun, mx);
                    const float fsc = __builtin_amdgcn_exp2f(mrun - mnew);
                    lrun *= fsc;
#pragma unroll
                    for (int dn = 0; dn < 4; ++dn) o[dn] *= fsc;
                    mrun = mnew;
                }
                float rs = 0.0f;
#pragma unroll
                for (int an = 0; an < 4; ++an)
#pragma unroll
                    for (int i = 0; i < 4; ++i) {
                        p[an][i] = __builtin_amdgcn_exp2f(p[an][i] - mrun);
                        rs += p[an][i];
                    }
                rs += __shfl_xor(rs, 16);
                rs += __shfl_xor(rs, 32);
                lrun += rs;
                const int ql = lane & 15;
                char* pbs = (char*)Ps[wid] + ql * 128;
                const int xr = (ql & 7) << 4;
                const int gb = (lane >> 4) << 3;
#pragma unroll
                for (int an = 0; an < 4; ++an) {
                    bf16x4v pk;
                    pk[0] = (__bf16)p[an][0]; pk[1] = (__bf16)p[an][1];
                    pk[2] = (__bf16)p[an][2]; pk[3] = (__bf16)p[an][3];
                    *(bf16x4v*)(pbs + ((an * 32 + gb) ^ xr)) = pk;
                }
                __builtin_amdgcn_s_setprio(1);
#pragma unroll
                for (int kf = 0; kf < 2; ++kf) {
                    bf16x8 vf[4], pf;
#pragma unroll
                    for (int dn = 0; dn < 4; ++dn) {
                        const int r = dn * 16 + (lane & 15);
                        vf[dn] = *(const bf16x8*)((const char*)Vs[cur] + r * 128 + ((kf * 64 + (lane >> 4) * 16) ^ ((r & 7) << 4)));
                    }
                    {
                        const int qlr = lane & 15;
                        pf = *(const bf16x8*)((const char*)Ps[wid] + qlr * 128 + ((kf * 64 + (lane >> 4) * 16) ^ ((qlr & 7) << 4)));
                    }
#pragma unroll
                    for (int dn = 0; dn < 4; ++dn)
                        o[dn] = __builtin_amdgcn_mfma_f32_16x16x32_bf16(vf[dn], pf, o[dn], 0, 0, 0);
                }
                __builtin_amdgcn_s_setprio(0);
            }
            __syncthreads();
        }

        {
            const float inv = 1.0f / lrun;
            const int qg = qw + (lane & 15);
            unsigned short* yrow = yb + (size_t)(b * SEQ + qg) * CDIM + h * 64;
#pragma unroll
            for (int dn = 0; dn < 4; ++dn) {
                const int d = dn * 16 + ((lane >> 4) << 2);
                bf16x4v pk;
                pk[0] = (__bf16)(o[dn][0] * inv);
                pk[1] = (__bf16)(o[dn][1] * inv);
                pk[2] = (__bf16)(o[dn][2] * inv);
                pk[3] = (__bf16)(o[dn][3] * inv);
                *(bf16x4v*)(yrow + d) = pk;
            }
        }
        // after the final __syncthreads of the kt loop all waves have drained
        // their LDS reads; epilogue is register/global only, so next half's
        // stage(0,0) into Ks[0]/Vs[0] is race-free.
    }
}

// ---------------- host ----------------

extern "C" void kernel_launch(void* const* d_in, const int* in_sizes, int n_in,
                              void* d_out, int out_size, void* d_ws, size_t ws_size,
                              hipStream_t stream) {
    (void)in_sizes; (void)n_in; (void)out_size; (void)ws_size;
    const float* x  = (const float*)d_in[0];
    const float* Wq = (const float*)d_in[1];
    const float* bq = (const float*)d_in[2];
    const float* Wk = (const float*)d_in[3];
    const float* bk = (const float*)d_in[4];
    const float* Wv = (const float*)d_in[5];
    const float* bv = (const float*)d_in[6];
    const float* Wp = (const float*)d_in[7];
    const float* bp = (const float*)d_in[8];
    float* out = (float*)d_out;

    char* ws = (char*)d_ws;
    size_t off = 0;
    auto take = [&](size_t bytes) -> char* {
        char* p = ws + off;
        off = (off + bytes + 255) & ~(size_t)255;
        return p;
    };
    float2* cstab = (float2*)take((size_t)SEQ * 32 * 8);
    unsigned short* xb   = (unsigned short*)take((size_t)4096 * 1024 * 2);
    unsigned short* wqkv = (unsigned short*)take((size_t)3 * 1024 * 1024 * 2);
    unsigned short* wpb  = (unsigned short*)take((size_t)1024 * 1024 * 2);
    unsigned short* qbuf = (unsigned short*)take((size_t)32 * SEQ * HDIM * 2);
    unsigned short* kbuf = (unsigned short*)take((size_t)32 * SEQ * HDIM * 2);
    unsigned short* vtb  = (unsigned short*)take((size_t)32 * HDIM * SEQ * 2);
    unsigned short* yb   = (unsigned short*)take((size_t)4096 * 1024 * 2);

    // fused converts + rope table: 2097152 + 65536 threads = 8448 blocks
    cvt_rope_all<<<8448, 256, 0, stream>>>(x, Wq, Wk, Wv, Wp, xb, wqkv, wpb, cstab);

    dim3 g0(24, 32);
    gemm_bt<0, 128><<<g0, 256, 0, stream>>>(xb, wqkv, bq, bk, bv, qbuf, kbuf, vtb, nullptr, cstab);
    dim3 g1(16, 32);
    attn_kernel<<<g1, 256, 0, stream>>>(qbuf, kbuf, vtb, yb);
    dim3 g2(8, 64);
    gemm_bt<1, 64><<<g2, 256, 0, stream>>>(yb, wpb, bp, nullptr, nullptr, nullptr, nullptr, nullptr, out, cstab);
}

// Round 15
// 129.847 us; speedup vs baseline: 1.0493x; 1.0493x over previous
//
#include <hip/hip_runtime.h>

#define SEQ 2048
#define CDIM 1024
#define NHEAD 16
#define HDIM 64

typedef __bf16 bf16x8 __attribute__((ext_vector_type(8)));
typedef __bf16 bf16x4v __attribute__((ext_vector_type(4)));
typedef float f32x4 __attribute__((ext_vector_type(4)));

typedef const __attribute__((address_space(1))) char* gcp_t;
typedef __attribute__((address_space(3))) char* lcp_t;

__device__ __forceinline__ void gload16(const void* g, void* l) {
    __builtin_amdgcn_global_load_lds((gcp_t)g, (lcp_t)l, 16, 0, 0);
}

__device__ __forceinline__ unsigned short f2bf(float f) {
    unsigned int u = __float_as_uint(f);
    u += 0x7fffu + ((u >> 16) & 1u);
    return (unsigned short)(u >> 16);
}

// 64B-row LDS swizzle (proven zero bank conflicts r6/r7)
__device__ __forceinline__ int swz16(int r) { return ((r >> 1) & 3) << 4; }

// ---------------- fused precompute: bf16 converts + RoPE table ------------
__global__ void cvt_rope_all(const float* __restrict__ x,
                             const float* __restrict__ Wq, const float* __restrict__ Wk,
                             const float* __restrict__ Wv, const float* __restrict__ Wp,
                             unsigned short* __restrict__ xb,
                             unsigned short* __restrict__ wqkv, unsigned short* __restrict__ wpb,
                             float2* __restrict__ cstab) {
    int i = blockIdx.x * blockDim.x + threadIdx.x;
    if (i < 2097152) {
        const float* s;
        unsigned short* d;
        int r;
        if (i < 1048576) { s = x; d = xb; r = i; }
        else {
            int j = i - 1048576;
            int which = j >> 18; r = j & 262143;
            s = (which == 0) ? Wq : (which == 1) ? Wk : (which == 2) ? Wv : Wp;
            d = (which < 3) ? (wqkv + (size_t)which * 1048576) : wpb;
        }
        float4 v = ((const float4*)s)[r];
        ushort4 o;
        o.x = f2bf(v.x); o.y = f2bf(v.y); o.z = f2bf(v.z); o.w = f2bf(v.w);
        ((ushort4*)d)[r] = o;
    } else {
        int idx = i - 2097152;          // 0 .. 65535
        int j = idx & 31, t = idx >> 5;
        // faithful to ref: theta = 1/10000**(-2*(j-1)/64), f32 roundings kept
        float e = -2.0f * ((float)j - 1.0f) / 64.0f;
        float denom = (float)pow(10000.0, (double)e);
        float theta = 1.0f / denom;
        float ang = (float)t * theta;
        cstab[idx] = make_float2(cosf(ang), sinf(ang));
    }
}

// ---------------- QKV GEMM: 256M x 192N tile, BK=64, 8 waves (r10 exact) --
// C = x * Wqkv^T (M=4096, N=3072, K=1024). 16x16 = 256 blocks = 1/CU, full
// coverage, zero tail. LDS 112KB: As[2][256x128B] + Bs2[2][192x128B].
// Per K-tile: issue ALL 7 prefetch gload16 for t+1 FIRST, then ds_reads +
// 48 MFMA/wave, then one vmcnt(0)+s_barrier (compute covers load latency).
// 128B rows: XOR byte ^= (row&7)<<4 on pre-swizzled global source and
// identically on ds_read (zero conflicts measured).
// Epilogue: bias + RoPE; q pre-scaled 0.125*log2e; k [B,H,T,D]; v^T [B,H,D,T].
__global__ __launch_bounds__(512, 1) void gemm_qkv(
    const unsigned short* __restrict__ A, const unsigned short* __restrict__ Bm,
    const float* __restrict__ b0, const float* __restrict__ b1, const float* __restrict__ b2,
    unsigned short* __restrict__ qb, unsigned short* __restrict__ kb,
    unsigned short* __restrict__ vtb, const float2* __restrict__ cstab)
{
    constexpr int NT = 16;                 // K/64 K-tiles
    __shared__ __align__(16) char As[2][256 * 128];
    __shared__ __align__(16) char Bs2[2][192 * 128];
    const int tid = threadIdx.x, lane = tid & 63, wid = tid >> 6;
    const int wr = wid >> 2, wc = wid & 3;   // 2M x 4N wave grid; 128x48 per wave
    const int bid = blockIdx.x;
    const int swz = (bid & 7) * 32 + (bid >> 3);   // XCD-bijective (256%8==0)
    const int mt = swz >> 4, ntl = swz & 15;
    const int m0 = mt * 256, n0 = ntl * 192;

    f32x4 acc[8][3] = {};

    const char* Ag = (const char*)A + (size_t)m0 * 2048;
    const char* Bg = (const char*)Bm + (size_t)n0 * 2048;
    const int r0 = tid >> 3, cb = (tid & 7) * 16;

    auto stage = [&](int k0, int bufi) {
#pragma unroll
        for (int v = 0; v < 4; ++v) {
            const int r = r0 + 64 * v;
            gload16(Ag + (size_t)r * 2048 + k0 * 2 + (cb ^ ((r & 7) << 4)),
                    As[bufi] + v * 8192 + wid * 1024);
        }
#pragma unroll
        for (int v = 0; v < 3; ++v) {
            const int r = r0 + 64 * v;
            gload16(Bg + (size_t)r * 2048 + k0 * 2 + (cb ^ ((r & 7) << 4)),
                    Bs2[bufi] + v * 8192 + wid * 1024);
        }
    };

    stage(0, 0);
    asm volatile("s_waitcnt vmcnt(0)" ::: "memory");
    __builtin_amdgcn_s_barrier();

    for (int t = 0; t < NT; ++t) {
        const int cur = t & 1;
        if (t + 1 < NT) stage((t + 1) * 64, cur ^ 1);   // front-loaded prefetch
        const char* Ac = As[cur];
        const char* Bc = Bs2[cur];
#pragma unroll
        for (int kf = 0; kf < 2; ++kf) {
            bf16x8 bfr[3];
#pragma unroll
            for (int fc = 0; fc < 3; ++fc) {
                const int r = wc * 48 + fc * 16 + (lane & 15);
                bfr[fc] = *(const bf16x8*)(Bc + r * 128 + ((kf * 64 + (lane >> 4) * 16) ^ ((r & 7) << 4)));
            }
            __builtin_amdgcn_s_setprio(1);
#pragma unroll
            for (int fr = 0; fr < 8; ++fr) {
                const int r = wr * 128 + fr * 16 + (lane & 15);
                bf16x8 af = *(const bf16x8*)(Ac + r * 128 + ((kf * 64 + (lane >> 4) * 16) ^ ((r & 7) << 4)));
#pragma unroll
                for (int fc = 0; fc < 3; ++fc)
                    acc[fr][fc] = __builtin_amdgcn_mfma_f32_16x16x32_bf16(af, bfr[fc], acc[fr][fc], 0, 0, 0);
            }
            __builtin_amdgcn_s_setprio(0);
        }
        asm volatile("s_waitcnt vmcnt(0)" ::: "memory");
        __builtin_amdgcn_s_barrier();
    }

    // epilogue: bias + RoPE, scatter q/k/v^T
    const float QSCL = 0.18033688011112042f;  // 0.125 * log2(e)
#pragma unroll
    for (int fc = 0; fc < 3; ++fc) {
        const int ng = n0 + wc * 48 + fc * 16 + (lane & 15);
        const int which = ng >> 10, nl = ng & 1023;
        const int h = nl >> 6, d = nl & 63;
        const float* bptr = (which == 0) ? b0 : (which == 1) ? b1 : b2;
        const float bias = bptr[nl];
        if (which < 2) {
            unsigned short* dst = (which == 0) ? qb : kb;
            const float qs = (which == 0) ? QSCL : 1.0f;
            const int j = d >> 1;
#pragma unroll
            for (int fr = 0; fr < 8; ++fr) {
#pragma unroll
                for (int i = 0; i < 4; ++i) {
                    const int row = m0 + wr * 128 + fr * 16 + (lane >> 4) * 4 + i;
                    const int bb = row >> 11, tt = row & 2047;
                    float v = acc[fr][fc][i] + bias;
                    float pp = __shfl_xor(v, 1);
                    const float2 cs = cstab[tt * 32 + j];
                    v = (d & 1) ? fmaf(v, cs.x, pp * cs.y) : fmaf(v, cs.x, -pp * cs.y);
                    dst[((size_t)((bb * 16 + h) * 2048 + tt)) * 64 + d] = f2bf(v * qs);
                }
            }
        } else {
#pragma unroll
            for (int fr = 0; fr < 8; ++fr) {
                const int rowb = m0 + wr * 128 + fr * 16 + (lane >> 4) * 4;
                const int bb = rowb >> 11, tt = rowb & 2047;
                ushort4 pk;
                pk.x = f2bf(acc[fr][fc][0] + bias);
                pk.y = f2bf(acc[fr][fc][1] + bias);
                pk.z = f2bf(acc[fr][fc][2] + bias);
                pk.w = f2bf(acc[fr][fc][3] + bias);
                *(ushort4*)(vtb + ((size_t)((bb * 16 + h) * 64 + d)) * 2048 + tt) = pk;
            }
        }
    }
}

// ---------------- proj GEMM: 64x128 2-phase dbuf + swz16 (r7/r10 exact) ---
template <int MODE, int BM>
__global__ __launch_bounds__(256) void gemm_bt(
    const unsigned short* __restrict__ A, const unsigned short* __restrict__ Bm,
    const float* __restrict__ b0,
    float* __restrict__ outf)
{
    constexpr int K = 1024;
    constexpr int NIT = K / 32;
    constexpr int NR = (BM == 128) ? 4 : 2;
    __shared__ __align__(16) char As[2][BM * 64];
    __shared__ __align__(16) char Bs[2][128 * 64];
    const int tid = threadIdx.x, lane = tid & 63, wid = tid >> 6;
    const int m0 = blockIdx.y * BM, n0 = blockIdx.x * 128;
    const int wr = (BM == 128) ? ((wid >> 1) * 64) : 0;
    const int wc = (BM == 128) ? ((wid & 1) * 64) : (wid * 32);

    f32x4 acc[4][NR] = {};

    const char* Ag = (const char*)(A + (size_t)m0 * K);
    const char* Bg = (const char*)(Bm + (size_t)n0 * K);
    const int r0 = tid >> 2, cb = (tid & 3) * 16;
    const int ldsw = wid << 10;

    auto stage = [&](int k0, int bufi) {
        char* Ad = As[bufi];
        char* Bd = Bs[bufi];
        gload16(Ag + (size_t)r0 * 2048 + k0 * 2 + (cb ^ swz16(r0)), Ad + ldsw);
        if constexpr (BM == 128)
            gload16(Ag + (size_t)(r0 + 64) * 2048 + k0 * 2 + (cb ^ swz16(r0 + 64)), Ad + 4096 + ldsw);
        gload16(Bg + (size_t)r0 * 2048 + k0 * 2 + (cb ^ swz16(r0)), Bd + ldsw);
        gload16(Bg + (size_t)(r0 + 64) * 2048 + k0 * 2 + (cb ^ swz16(r0 + 64)), Bd + 4096 + ldsw);
    };

    stage(0, 0);
    __syncthreads();

    for (int it = 0; it < NIT; ++it) {
        const int cur = it & 1;
        if (it + 1 < NIT) stage((it + 1) * 32, cur ^ 1);
        const char* Ac = As[cur];
        const char* Bc = Bs[cur];
        const int fs = (lane >> 4) * 16;
        bf16x8 af[4], bfr[NR];
#pragma unroll
        for (int am = 0; am < 4; ++am) {
            const int r = wr + am * 16 + (lane & 15);
            af[am] = *(const bf16x8*)(Ac + r * 64 + (fs ^ swz16(r)));
        }
#pragma unroll
        for (int an = 0; an < NR; ++an) {
            const int r = wc + an * 16 + (lane & 15);
            bfr[an] = *(const bf16x8*)(Bc + r * 64 + (fs ^ swz16(r)));
        }
#pragma unroll
        for (int am = 0; am < 4; ++am)
#pragma unroll
            for (int an = 0; an < NR; ++an)
                acc[am][an] = __builtin_amdgcn_mfma_f32_16x16x32_bf16(af[am], bfr[an], acc[am][an], 0, 0, 0);
        __syncthreads();
    }

#pragma unroll
    for (int an = 0; an < NR; ++an) {
        const int col = n0 + wc + an * 16 + (lane & 15);
        const float bias = b0[col];
#pragma unroll
        for (int am = 0; am < 4; ++am)
#pragma unroll
            for (int i = 0; i < 4; ++i) {
                const int row = m0 + wr + am * 16 + (lane >> 4) * 4 + i;
                outf[(size_t)row * 1024 + col] = acc[am][an][i] + bias;
            }
    }
}

// ---------------- flash attention (round-4 kernel, best measured) ---------
// grid: (32 q-tiles of 64, 32 bh); qtile reversed for bh>=16 so each CU's four
// resident blocks have complementary causal lengths. 4 waves, 16 q rows each.
// K staged [64 kv][64 d], V^T staged [64 d][64 kv], double-buffered,
// XOR-swizzled via pre-swizzled global source. LDS 40KB -> 4 blocks/CU.
__global__ __launch_bounds__(256) void attn_kernel(
    const unsigned short* __restrict__ qb, const unsigned short* __restrict__ kb,
    const unsigned short* __restrict__ vtb, unsigned short* __restrict__ yb)
{
    __shared__ __align__(16) unsigned short Ks[2][64 * 64];
    __shared__ __align__(16) unsigned short Vs[2][64 * 64];
    __shared__ __align__(16) unsigned short Ps[4][16 * 64];
    const int tid = threadIdx.x, lane = tid & 63, wid = tid >> 6;
    const int bh = blockIdx.y;
    const int b = bh >> 4, h = bh & 15;
    const int qt = (bh & 16) ? (31 - blockIdx.x) : blockIdx.x;
    const int q0 = qt * 64;
    const int qw = q0 + wid * 16;
    const unsigned short* Qg = qb + (size_t)bh * SEQ * HDIM;
    const char* Kg = (const char*)(kb + (size_t)bh * SEQ * HDIM);
    const char* Vg = (const char*)(vtb + (size_t)bh * HDIM * SEQ);

    bf16x8 qf[2];
#pragma unroll
    for (int kf = 0; kf < 2; ++kf)
        qf[kf] = *(const bf16x8*)(Qg + (size_t)(qw + (lane & 15)) * 64 + kf * 32 + (lane >> 4) * 8);

    f32x4 o[4] = {};                 // o[dn] : O^T[d][q]
    float mrun = -3e38f;
    float lrun = 0.0f;

    const int nt = qt + 1;
    const int cr0 = tid >> 3, cc0 = ((tid & 7) * 16) ^ ((cr0 & 7) << 4);
    const int cr1 = cr0 + 32, cc1 = ((tid & 7) * 16) ^ ((cr1 & 7) << 4);
    const int ldsw = wid << 10;

    auto stage = [&](int kt, int bufi) {
        const size_t kv0 = (size_t)kt * 64;
        gload16(Kg + (kv0 + cr0) * 128 + cc0, (char*)Ks[bufi] + ldsw);
        gload16(Kg + (kv0 + cr1) * 128 + cc1, (char*)Ks[bufi] + 4096 + ldsw);
        gload16(Vg + (size_t)cr0 * 4096 + kv0 * 2 + cc0, (char*)Vs[bufi] + ldsw);
        gload16(Vg + (size_t)cr1 * 4096 + kv0 * 2 + cc1, (char*)Vs[bufi] + 4096 + ldsw);
    };

    stage(0, 0);
    __syncthreads();

    for (int kt = 0; kt < nt; ++kt) {
        const int cur = kt & 1;
        if (kt + 1 < nt) stage(kt + 1, cur ^ 1);
        const int kv0 = kt * 64;
        {
            f32x4 s[4] = {};
            __builtin_amdgcn_s_setprio(1);
#pragma unroll
            for (int kf = 0; kf < 2; ++kf) {
                bf16x8 kfr[4];
#pragma unroll
                for (int an = 0; an < 4; ++an) {
                    const int r = an * 16 + (lane & 15);
                    kfr[an] = *(const bf16x8*)((const char*)Ks[cur] + r * 128 + ((kf * 64 + (lane >> 4) * 16) ^ ((r & 7) << 4)));
                }
#pragma unroll
                for (int an = 0; an < 4; ++an)
                    s[an] = __builtin_amdgcn_mfma_f32_16x16x32_bf16(kfr[an], qf[kf], s[an], 0, 0, 0);
            }
            __builtin_amdgcn_s_setprio(0);
            const bool need_mask = (kv0 + 63 > qw);
            const int qg = qw + (lane & 15);
            const int kbase = kv0 + ((lane >> 4) << 2);
            float p[4][4];
            float mx = -3e38f;
#pragma unroll
            for (int an = 0; an < 4; ++an)
#pragma unroll
                for (int i = 0; i < 4; ++i) {
                    float v = s[an][i];
                    if (need_mask && (kbase + an * 16 + i > qg)) v = -3e38f;
                    p[an][i] = v;
                    mx = fmaxf(mx, v);
                }
            mx = fmaxf(mx, __shfl_xor(mx, 16));
            mx = fmaxf(mx, __shfl_xor(mx, 32));
            if (!__all(mx <= mrun + 8.0f)) {
                const float mnew = fmaxf(mrun, mx);
                const float fsc = __builtin_amdgcn_exp2f(mrun - mnew);
                lrun *= fsc;
#pragma unroll
                for (int dn = 0; dn < 4; ++dn) o[dn] *= fsc;
                mrun = mnew;
            }
            float rs = 0.0f;
#pragma unroll
            for (int an = 0; an < 4; ++an)
#pragma unroll
                for (int i = 0; i < 4; ++i) {
                    p[an][i] = __builtin_amdgcn_exp2f(p[an][i] - mrun);
                    rs += p[an][i];
                }
            rs += __shfl_xor(rs, 16);
            rs += __shfl_xor(rs, 32);
            lrun += rs;
            const int ql = lane & 15;
            char* pbs = (char*)Ps[wid] + ql * 128;
            const int xr = (ql & 7) << 4;
            const int gb = (lane >> 4) << 3;
#pragma unroll
            for (int an = 0; an < 4; ++an) {
                bf16x4v pk;
                pk[0] = (__bf16)p[an][0]; pk[1] = (__bf16)p[an][1];
                pk[2] = (__bf16)p[an][2]; pk[3] = (__bf16)p[an][3];
                *(bf16x4v*)(pbs + ((an * 32 + gb) ^ xr)) = pk;
            }
            __builtin_amdgcn_s_setprio(1);
#pragma unroll
            for (int kf = 0; kf < 2; ++kf) {
                bf16x8 vf[4], pf;
#pragma unroll
                for (int dn = 0; dn < 4; ++dn) {
                    const int r = dn * 16 + (lane & 15);
                    vf[dn] = *(const bf16x8*)((const char*)Vs[cur] + r * 128 + ((kf * 64 + (lane >> 4) * 16) ^ ((r & 7) << 4)));
                }
                {
                    const int qlr = lane & 15;
                    pf = *(const bf16x8*)((const char*)Ps[wid] + qlr * 128 + ((kf * 64 + (lane >> 4) * 16) ^ ((qlr & 7) << 4)));
                }
#pragma unroll
                for (int dn = 0; dn < 4; ++dn)
                    o[dn] = __builtin_amdgcn_mfma_f32_16x16x32_bf16(vf[dn], pf, o[dn], 0, 0, 0);
            }
            __builtin_amdgcn_s_setprio(0);
        }
        __syncthreads();
    }

    {
        const float inv = 1.0f / lrun;
        const int qg = qw + (lane & 15);
        unsigned short* yrow = yb + (size_t)(b * SEQ + qg) * CDIM + h * 64;
#pragma unroll
        for (int dn = 0; dn < 4; ++dn) {
            const int d = dn * 16 + ((lane >> 4) << 2);
            bf16x4v pk;
            pk[0] = (__bf16)(o[dn][0] * inv);
            pk[1] = (__bf16)(o[dn][1] * inv);
            pk[2] = (__bf16)(o[dn][2] * inv);
            pk[3] = (__bf16)(o[dn][3] * inv);
            *(bf16x4v*)(yrow + d) = pk;
        }
    }
}

// ---------------- host ----------------

extern "C" void kernel_launch(void* const* d_in, const int* in_sizes, int n_in,
                              void* d_out, int out_size, void* d_ws, size_t ws_size,
                              hipStream_t stream) {
    (void)in_sizes; (void)n_in; (void)out_size; (void)ws_size;
    const float* x  = (const float*)d_in[0];
    const float* Wq = (const float*)d_in[1];
    const float* bq = (const float*)d_in[2];
    const float* Wk = (const float*)d_in[3];
    const float* bk = (const float*)d_in[4];
    const float* Wv = (const float*)d_in[5];
    const float* bv = (const float*)d_in[6];
    const float* Wp = (const float*)d_in[7];
    const float* bp = (const float*)d_in[8];
    float* out = (float*)d_out;

    char* ws = (char*)d_ws;
    size_t off = 0;
    auto take = [&](size_t bytes) -> char* {
        char* p = ws + off;
        off = (off + bytes + 255) & ~(size_t)255;
        return p;
    };
    float2* cstab = (float2*)take((size_t)SEQ * 32 * 8);
    unsigned short* xb   = (unsigned short*)take((size_t)4096 * 1024 * 2);
    unsigned short* wqkv = (unsigned short*)take((size_t)3 * 1024 * 1024 * 2);
    unsigned short* wpb  = (unsigned short*)take((size_t)1024 * 1024 * 2);
    unsigned short* qbuf = (unsigned short*)take((size_t)32 * SEQ * HDIM * 2);
    unsigned short* kbuf = (unsigned short*)take((size_t)32 * SEQ * HDIM * 2);
    unsigned short* vtb  = (unsigned short*)take((size_t)32 * HDIM * SEQ * 2);
    unsigned short* yb   = (unsigned short*)take((size_t)4096 * 1024 * 2);

    // fused converts + rope table: 2097152 + 65536 threads = 8448 blocks
    cvt_rope_all<<<8448, 256, 0, stream>>>(x, Wq, Wk, Wv, Wp, xb, wqkv, wpb, cstab);

    gemm_qkv<<<256, 512, 0, stream>>>(xb, wqkv, bq, bk, bv, qbuf, kbuf, vtb, cstab);
    dim3 g1(32, 32);
    attn_kernel<<<g1, 256, 0, stream>>>(qbuf, kbuf, vtb, yb);
    dim3 g2(8, 64);
    gemm_bt<1, 64><<<g2, 256, 0, stream>>>(yb, wpb, bp, out);
}

// Round 16
// 128.672 us; speedup vs baseline: 1.0589x; 1.0091x over previous
//
#include <hip/hip_runtime.h>

#define SEQ 2048
#define CDIM 1024
#define NHEAD 16
#define HDIM 64

typedef __bf16 bf16x8 __attribute__((ext_vector_type(8)));
typedef __bf16 bf16x4v __attribute__((ext_vector_type(4)));
typedef float f32x4 __attribute__((ext_vector_type(4)));

typedef const __attribute__((address_space(1))) char* gcp_t;
typedef __attribute__((address_space(3))) char* lcp_t;

__device__ __forceinline__ void gload16(const void* g, void* l) {
    __builtin_amdgcn_global_load_lds((gcp_t)g, (lcp_t)l, 16, 0, 0);
}

__device__ __forceinline__ unsigned short f2bf(float f) {
    unsigned int u = __float_as_uint(f);
    u += 0x7fffu + ((u >> 16) & 1u);
    return (unsigned short)(u >> 16);
}

// 64B-row LDS swizzle (proven zero bank conflicts r6/r7)
__device__ __forceinline__ int swz16(int r) { return ((r >> 1) & 3) << 4; }

// ---------------- fused precompute: bf16 converts + RoPE table ------------
__global__ void cvt_rope_all(const float* __restrict__ x,
                             const float* __restrict__ Wq, const float* __restrict__ Wk,
                             const float* __restrict__ Wv, const float* __restrict__ Wp,
                             unsigned short* __restrict__ xb,
                             unsigned short* __restrict__ wqkv, unsigned short* __restrict__ wpb,
                             float2* __restrict__ cstab) {
    int i = blockIdx.x * blockDim.x + threadIdx.x;
    if (i < 2097152) {
        const float* s;
        unsigned short* d;
        int r;
        if (i < 1048576) { s = x; d = xb; r = i; }
        else {
            int j = i - 1048576;
            int which = j >> 18; r = j & 262143;
            s = (which == 0) ? Wq : (which == 1) ? Wk : (which == 2) ? Wv : Wp;
            d = (which < 3) ? (wqkv + (size_t)which * 1048576) : wpb;
        }
        float4 v = ((const float4*)s)[r];
        ushort4 o;
        o.x = f2bf(v.x); o.y = f2bf(v.y); o.z = f2bf(v.z); o.w = f2bf(v.w);
        ((ushort4*)d)[r] = o;
    } else {
        int idx = i - 2097152;          // 0 .. 65535
        int j = idx & 31, t = idx >> 5;
        // faithful to ref: theta = 1/10000**(-2*(j-1)/64), f32 roundings kept
        float e = -2.0f * ((float)j - 1.0f) / 64.0f;
        float denom = (float)pow(10000.0, (double)e);
        float theta = 1.0f / denom;
        float ang = (float)t * theta;
        cstab[idx] = make_float2(cosf(ang), sinf(ang));
    }
}

// ---------------- QKV GEMM: 256M x 192N tile, BK=64, 8 waves --------------
// r15 kernel with ONE change: counted-vmcnt top-wait instead of bottom
// drain-to-0 (T4). Loop: stage(t+1) -> vmcnt(7) [tile t's loads, issued a
// full iteration ago, are the 7-oldest -> in-order retirement guarantees
// they landed; t+1's 7 stay in flight] -> barrier B1 [cross-wave visibility]
// -> compute(t) -> barrier B2 [all waves done reading tile t before iter
// t+1's stage overwrites buf[t&1]]. ds_reads retire before each wave's last
// MFMA, hence before B2 -> race-free with 2 buffers.
__global__ __launch_bounds__(512, 1) void gemm_qkv(
    const unsigned short* __restrict__ A, const unsigned short* __restrict__ Bm,
    const float* __restrict__ b0, const float* __restrict__ b1, const float* __restrict__ b2,
    unsigned short* __restrict__ qb, unsigned short* __restrict__ kb,
    unsigned short* __restrict__ vtb, const float2* __restrict__ cstab)
{
    constexpr int NT = 16;                 // K/64 K-tiles
    __shared__ __align__(16) char As[2][256 * 128];
    __shared__ __align__(16) char Bs2[2][192 * 128];
    const int tid = threadIdx.x, lane = tid & 63, wid = tid >> 6;
    const int wr = wid >> 2, wc = wid & 3;   // 2M x 4N wave grid; 128x48 per wave
    const int bid = blockIdx.x;
    const int swz = (bid & 7) * 32 + (bid >> 3);   // XCD-bijective (256%8==0)
    const int mt = swz >> 4, ntl = swz & 15;
    const int m0 = mt * 256, n0 = ntl * 192;

    f32x4 acc[8][3] = {};

    const char* Ag = (const char*)A + (size_t)m0 * 2048;
    const char* Bg = (const char*)Bm + (size_t)n0 * 2048;
    const int r0 = tid >> 3, cb = (tid & 7) * 16;

    auto stage = [&](int k0, int bufi) {
#pragma unroll
        for (int v = 0; v < 4; ++v) {
            const int r = r0 + 64 * v;
            gload16(Ag + (size_t)r * 2048 + k0 * 2 + (cb ^ ((r & 7) << 4)),
                    As[bufi] + v * 8192 + wid * 1024);
        }
#pragma unroll
        for (int v = 0; v < 3; ++v) {
            const int r = r0 + 64 * v;
            gload16(Bg + (size_t)r * 2048 + k0 * 2 + (cb ^ ((r & 7) << 4)),
                    Bs2[bufi] + v * 8192 + wid * 1024);
        }
    };

    stage(0, 0);    // tile 0 in flight (7 loads/wave)

    for (int t = 0; t < NT; ++t) {
        const int cur = t & 1;
        if (t + 1 < NT) {
            stage((t + 1) * 64, cur ^ 1);   // issue next tile (7 more loads)
            // wait for tile t's loads (oldest 7); t+1's 7 remain in flight
            asm volatile("s_waitcnt vmcnt(7)" ::: "memory");
        } else {
            asm volatile("s_waitcnt vmcnt(0)" ::: "memory");
        }
        __builtin_amdgcn_s_barrier();       // B1: tile t visible to all waves
        const char* Ac = As[cur];
        const char* Bc = Bs2[cur];
#pragma unroll
        for (int kf = 0; kf < 2; ++kf) {
            bf16x8 bfr[3];
#pragma unroll
            for (int fc = 0; fc < 3; ++fc) {
                const int r = wc * 48 + fc * 16 + (lane & 15);
                bfr[fc] = *(const bf16x8*)(Bc + r * 128 + ((kf * 64 + (lane >> 4) * 16) ^ ((r & 7) << 4)));
            }
            __builtin_amdgcn_s_setprio(1);
#pragma unroll
            for (int fr = 0; fr < 8; ++fr) {
                const int r = wr * 128 + fr * 16 + (lane & 15);
                bf16x8 af = *(const bf16x8*)(Ac + r * 128 + ((kf * 64 + (lane >> 4) * 16) ^ ((r & 7) << 4)));
#pragma unroll
                for (int fc = 0; fc < 3; ++fc)
                    acc[fr][fc] = __builtin_amdgcn_mfma_f32_16x16x32_bf16(af, bfr[fc], acc[fr][fc], 0, 0, 0);
            }
            __builtin_amdgcn_s_setprio(0);
        }
        if (t + 1 < NT) __builtin_amdgcn_s_barrier();   // B2: done reading tile t
    }

    // epilogue: bias + RoPE, scatter q/k/v^T (r15 exact)
    const float QSCL = 0.18033688011112042f;  // 0.125 * log2(e)
#pragma unroll
    for (int fc = 0; fc < 3; ++fc) {
        const int ng = n0 + wc * 48 + fc * 16 + (lane & 15);
        const int which = ng >> 10, nl = ng & 1023;
        const int h = nl >> 6, d = nl & 63;
        const float* bptr = (which == 0) ? b0 : (which == 1) ? b1 : b2;
        const float bias = bptr[nl];
        if (which < 2) {
            unsigned short* dst = (which == 0) ? qb : kb;
            const float qs = (which == 0) ? QSCL : 1.0f;
            const int j = d >> 1;
#pragma unroll
            for (int fr = 0; fr < 8; ++fr) {
#pragma unroll
                for (int i = 0; i < 4; ++i) {
                    const int row = m0 + wr * 128 + fr * 16 + (lane >> 4) * 4 + i;
                    const int bb = row >> 11, tt = row & 2047;
                    float v = acc[fr][fc][i] + bias;
                    float pp = __shfl_xor(v, 1);
                    const float2 cs = cstab[tt * 32 + j];
                    v = (d & 1) ? fmaf(v, cs.x, pp * cs.y) : fmaf(v, cs.x, -pp * cs.y);
                    dst[((size_t)((bb * 16 + h) * 2048 + tt)) * 64 + d] = f2bf(v * qs);
                }
            }
        } else {
#pragma unroll
            for (int fr = 0; fr < 8; ++fr) {
                const int rowb = m0 + wr * 128 + fr * 16 + (lane >> 4) * 4;
                const int bb = rowb >> 11, tt = rowb & 2047;
                ushort4 pk;
                pk.x = f2bf(acc[fr][fc][0] + bias);
                pk.y = f2bf(acc[fr][fc][1] + bias);
                pk.z = f2bf(acc[fr][fc][2] + bias);
                pk.w = f2bf(acc[fr][fc][3] + bias);
                *(ushort4*)(vtb + ((size_t)((bb * 16 + h) * 64 + d)) * 2048 + tt) = pk;
            }
        }
    }
}

// ---------------- proj GEMM: 64x128 2-phase dbuf + swz16 (r15 exact) ------
template <int MODE, int BM>
__global__ __launch_bounds__(256) void gemm_bt(
    const unsigned short* __restrict__ A, const unsigned short* __restrict__ Bm,
    const float* __restrict__ b0,
    float* __restrict__ outf)
{
    constexpr int K = 1024;
    constexpr int NIT = K / 32;
    constexpr int NR = (BM == 128) ? 4 : 2;
    __shared__ __align__(16) char As[2][BM * 64];
    __shared__ __align__(16) char Bs[2][128 * 64];
    const int tid = threadIdx.x, lane = tid & 63, wid = tid >> 6;
    const int m0 = blockIdx.y * BM, n0 = blockIdx.x * 128;
    const int wr = (BM == 128) ? ((wid >> 1) * 64) : 0;
    const int wc = (BM == 128) ? ((wid & 1) * 64) : (wid * 32);

    f32x4 acc[4][NR] = {};

    const char* Ag = (const char*)(A + (size_t)m0 * K);
    const char* Bg = (const char*)(Bm + (size_t)n0 * K);
    const int r0 = tid >> 2, cb = (tid & 3) * 16;
    const int ldsw = wid << 10;

    auto stage = [&](int k0, int bufi) {
        char* Ad = As[bufi];
        char* Bd = Bs[bufi];
        gload16(Ag + (size_t)r0 * 2048 + k0 * 2 + (cb ^ swz16(r0)), Ad + ldsw);
        if constexpr (BM == 128)
            gload16(Ag + (size_t)(r0 + 64) * 2048 + k0 * 2 + (cb ^ swz16(r0 + 64)), Ad + 4096 + ldsw);
        gload16(Bg + (size_t)r0 * 2048 + k0 * 2 + (cb ^ swz16(r0)), Bd + ldsw);
        gload16(Bg + (size_t)(r0 + 64) * 2048 + k0 * 2 + (cb ^ swz16(r0 + 64)), Bd + 4096 + ldsw);
    };

    stage(0, 0);
    __syncthreads();

    for (int it = 0; it < NIT; ++it) {
        const int cur = it & 1;
        if (it + 1 < NIT) stage((it + 1) * 32, cur ^ 1);
        const char* Ac = As[cur];
        const char* Bc = Bs[cur];
        const int fs = (lane >> 4) * 16;
        bf16x8 af[4], bfr[NR];
#pragma unroll
        for (int am = 0; am < 4; ++am) {
            const int r = wr + am * 16 + (lane & 15);
            af[am] = *(const bf16x8*)(Ac + r * 64 + (fs ^ swz16(r)));
        }
#pragma unroll
        for (int an = 0; an < NR; ++an) {
            const int r = wc + an * 16 + (lane & 15);
            bfr[an] = *(const bf16x8*)(Bc + r * 64 + (fs ^ swz16(r)));
        }
#pragma unroll
        for (int am = 0; am < 4; ++am)
#pragma unroll
            for (int an = 0; an < NR; ++an)
                acc[am][an] = __builtin_amdgcn_mfma_f32_16x16x32_bf16(af[am], bfr[an], acc[am][an], 0, 0, 0);
        __syncthreads();
    }

#pragma unroll
    for (int an = 0; an < NR; ++an) {
        const int col = n0 + wc + an * 16 + (lane & 15);
        const float bias = b0[col];
#pragma unroll
        for (int am = 0; am < 4; ++am)
#pragma unroll
            for (int i = 0; i < 4; ++i) {
                const int row = m0 + wr + am * 16 + (lane >> 4) * 4 + i;
                outf[(size_t)row * 1024 + col] = acc[am][an][i] + bias;
            }
    }
}

// ---------------- flash attention (round-4 kernel, best measured) ---------
__global__ __launch_bounds__(256) void attn_kernel(
    const unsigned short* __restrict__ qb, const unsigned short* __restrict__ kb,
    const unsigned short* __restrict__ vtb, unsigned short* __restrict__ yb)
{
    __shared__ __align__(16) unsigned short Ks[2][64 * 64];
    __shared__ __align__(16) unsigned short Vs[2][64 * 64];
    __shared__ __align__(16) unsigned short Ps[4][16 * 64];
    const int tid = threadIdx.x, lane = tid & 63, wid = tid >> 6;
    const int bh = blockIdx.y;
    const int b = bh >> 4, h = bh & 15;
    const int qt = (bh & 16) ? (31 - blockIdx.x) : blockIdx.x;
    const int q0 = qt * 64;
    const int qw = q0 + wid * 16;
    const unsigned short* Qg = qb + (size_t)bh * SEQ * HDIM;
    const char* Kg = (const char*)(kb + (size_t)bh * SEQ * HDIM);
    const char* Vg = (const char*)(vtb + (size_t)bh * HDIM * SEQ);

    bf16x8 qf[2];
#pragma unroll
    for (int kf = 0; kf < 2; ++kf)
        qf[kf] = *(const bf16x8*)(Qg + (size_t)(qw + (lane & 15)) * 64 + kf * 32 + (lane >> 4) * 8);

    f32x4 o[4] = {};                 // o[dn] : O^T[d][q]
    float mrun = -3e38f;
    float lrun = 0.0f;

    const int nt = qt + 1;
    const int cr0 = tid >> 3, cc0 = ((tid & 7) * 16) ^ ((cr0 & 7) << 4);
    const int cr1 = cr0 + 32, cc1 = ((tid & 7) * 16) ^ ((cr1 & 7) << 4);
    const int ldsw = wid << 10;

    auto stage = [&](int kt, int bufi) {
        const size_t kv0 = (size_t)kt * 64;
        gload16(Kg + (kv0 + cr0) * 128 + cc0, (char*)Ks[bufi] + ldsw);
        gload16(Kg + (kv0 + cr1) * 128 + cc1, (char*)Ks[bufi] + 4096 + ldsw);
        gload16(Vg + (size_t)cr0 * 4096 + kv0 * 2 + cc0, (char*)Vs[bufi] + ldsw);
        gload16(Vg + (size_t)cr1 * 4096 + kv0 * 2 + cc1, (char*)Vs[bufi] + 4096 + ldsw);
    };

    stage(0, 0);
    __syncthreads();

    for (int kt = 0; kt < nt; ++kt) {
        const int cur = kt & 1;
        if (kt + 1 < nt) stage(kt + 1, cur ^ 1);
        const int kv0 = kt * 64;
        {
            f32x4 s[4] = {};
            __builtin_amdgcn_s_setprio(1);
#pragma unroll
            for (int kf = 0; kf < 2; ++kf) {
                bf16x8 kfr[4];
#pragma unroll
                for (int an = 0; an < 4; ++an) {
                    const int r = an * 16 + (lane & 15);
                    kfr[an] = *(const bf16x8*)((const char*)Ks[cur] + r * 128 + ((kf * 64 + (lane >> 4) * 16) ^ ((r & 7) << 4)));
                }
#pragma unroll
                for (int an = 0; an < 4; ++an)
                    s[an] = __builtin_amdgcn_mfma_f32_16x16x32_bf16(kfr[an], qf[kf], s[an], 0, 0, 0);
            }
            __builtin_amdgcn_s_setprio(0);
            const bool need_mask = (kv0 + 63 > qw);
            const int qg = qw + (lane & 15);
            const int kbase = kv0 + ((lane >> 4) << 2);
            float p[4][4];
            float mx = -3e38f;
#pragma unroll
            for (int an = 0; an < 4; ++an)
#pragma unroll
                for (int i = 0; i < 4; ++i) {
                    float v = s[an][i];
                    if (need_mask && (kbase + an * 16 + i > qg)) v = -3e38f;
                    p[an][i] = v;
                    mx = fmaxf(mx, v);
                }
            mx = fmaxf(mx, __shfl_xor(mx, 16));
            mx = fmaxf(mx, __shfl_xor(mx, 32));
            if (!__all(mx <= mrun + 8.0f)) {
                const float mnew = fmaxf(mrun, mx);
                const float fsc = __builtin_amdgcn_exp2f(mrun - mnew);
                lrun *= fsc;
#pragma unroll
                for (int dn = 0; dn < 4; ++dn) o[dn] *= fsc;
                mrun = mnew;
            }
            float rs = 0.0f;
#pragma unroll
            for (int an = 0; an < 4; ++an)
#pragma unroll
                for (int i = 0; i < 4; ++i) {
                    p[an][i] = __builtin_amdgcn_exp2f(p[an][i] - mrun);
                    rs += p[an][i];
                }
            rs += __shfl_xor(rs, 16);
            rs += __shfl_xor(rs, 32);
            lrun += rs;
            const int ql = lane & 15;
            char* pbs = (char*)Ps[wid] + ql * 128;
            const int xr = (ql & 7) << 4;
            const int gb = (lane >> 4) << 3;
#pragma unroll
            for (int an = 0; an < 4; ++an) {
                bf16x4v pk;
                pk[0] = (__bf16)p[an][0]; pk[1] = (__bf16)p[an][1];
                pk[2] = (__bf16)p[an][2]; pk[3] = (__bf16)p[an][3];
                *(bf16x4v*)(pbs + ((an * 32 + gb) ^ xr)) = pk;
            }
            __builtin_amdgcn_s_setprio(1);
#pragma unroll
            for (int kf = 0; kf < 2; ++kf) {
                bf16x8 vf[4], pf;
#pragma unroll
                for (int dn = 0; dn < 4; ++dn) {
                    const int r = dn * 16 + (lane & 15);
                    vf[dn] = *(const bf16x8*)((const char*)Vs[cur] + r * 128 + ((kf * 64 + (lane >> 4) * 16) ^ ((r & 7) << 4)));
                }
                {
                    const int qlr = lane & 15;
                    pf = *(const bf16x8*)((const char*)Ps[wid] + qlr * 128 + ((kf * 64 + (lane >> 4) * 16) ^ ((qlr & 7) << 4)));
                }
#pragma unroll
                for (int dn = 0; dn < 4; ++dn)
                    o[dn] = __builtin_amdgcn_mfma_f32_16x16x32_bf16(vf[dn], pf, o[dn], 0, 0, 0);
            }
            __builtin_amdgcn_s_setprio(0);
        }
        __syncthreads();
    }

    {
        const float inv = 1.0f / lrun;
        const int qg = qw + (lane & 15);
        unsigned short* yrow = yb + (size_t)(b * SEQ + qg) * CDIM + h * 64;
#pragma unroll
        for (int dn = 0; dn < 4; ++dn) {
            const int d = dn * 16 + ((lane >> 4) << 2);
            bf16x4v pk;
            pk[0] = (__bf16)(o[dn][0] * inv);
            pk[1] = (__bf16)(o[dn][1] * inv);
            pk[2] = (__bf16)(o[dn][2] * inv);
            pk[3] = (__bf16)(o[dn][3] * inv);
            *(bf16x4v*)(yrow + d) = pk;
        }
    }
}

// ---------------- host ----------------

extern "C" void kernel_launch(void* const* d_in, const int* in_sizes, int n_in,
                              void* d_out, int out_size, void* d_ws, size_t ws_size,
                              hipStream_t stream) {
    (void)in_sizes; (void)n_in; (void)out_size; (void)ws_size;
    const float* x  = (const float*)d_in[0];
    const float* Wq = (const float*)d_in[1];
    const float* bq = (const float*)d_in[2];
    const float* Wk = (const float*)d_in[3];
    const float* bk = (const float*)d_in[4];
    const float* Wv = (const float*)d_in[5];
    const float* bv = (const float*)d_in[6];
    const float* Wp = (const float*)d_in[7];
    const float* bp = (const float*)d_in[8];
    float* out = (float*)d_out;

    char* ws = (char*)d_ws;
    size_t off = 0;
    auto take = [&](size_t bytes) -> char* {
        char* p = ws + off;
        off = (off + bytes + 255) & ~(size_t)255;
        return p;
    };
    float2* cstab = (float2*)take((size_t)SEQ * 32 * 8);
    unsigned short* xb   = (unsigned short*)take((size_t)4096 * 1024 * 2);
    unsigned short* wqkv = (unsigned short*)take((size_t)3 * 1024 * 1024 * 2);
    unsigned short* wpb  = (unsigned short*)take((size_t)1024 * 1024 * 2);
    unsigned short* qbuf = (unsigned short*)take((size_t)32 * SEQ * HDIM * 2);
    unsigned short* kbuf = (unsigned short*)take((size_t)32 * SEQ * HDIM * 2);
    unsigned short* vtb  = (unsigned short*)take((size_t)32 * HDIM * SEQ * 2);
    unsigned short* yb   = (unsigned short*)take((size_t)4096 * 1024 * 2);

    // fused converts + rope table: 2097152 + 65536 threads = 8448 blocks
    cvt_rope_all<<<8448, 256, 0, stream>>>(x, Wq, Wk, Wv, Wp, xb, wqkv, wpb, cstab);

    gemm_qkv<<<256, 512, 0, stream>>>(xb, wqkv, bq, bk, bv, qbuf, kbuf, vtb, cstab);
    dim3 g1(32, 32);
    attn_kernel<<<g1, 256, 0, stream>>>(qbuf, kbuf, vtb, yb);
    dim3 g2(8, 64);
    gemm_bt<1, 64><<<g2, 256, 0, stream>>>(yb, wpb, bp, out);
}